// Round 10
// baseline (160.431 us; speedup 1.0000x reference)
//
#include <hip/hip_runtime.h>
#include <hip/hip_bf16.h>
#include <math.h>

#define NH 8
#define HS 64
#define VOCAB 16384
#define QPH 2048                         // queries per head = b(4) * t(512)
#define NVG 8                            // vocab groups (2048 rows each)
// fold 1/sqrt(512) * log2(e) into Q so the epilogue is p = exp2(score)
#define QSCALE (0.04419417382415922f * 1.4426950408889634f)

typedef __attribute__((ext_vector_type(8))) short bf16x8;
typedef __attribute__((ext_vector_type(4))) float f32x4;

static __device__ __forceinline__ unsigned short f2bf(float f) {
    __hip_bfloat16 h = __float2bfloat16(f);
    unsigned short u;
    __builtin_memcpy(&u, &h, 2);
    return u;
}

static __device__ __forceinline__ float fexp2(float x) {
#if __has_builtin(__builtin_amdgcn_exp2f)
    return __builtin_amdgcn_exp2f(x);     // v_exp_f32 directly
#else
    return __expf(x * 0.6931471805599453f);
#endif
}

// async global->LDS. HW semantics (hard-won over R12/R16/R17):
//  - LDS dest operand = WAVE-UNIFORM base; HW adds lane*16 (divergent dest -> fault).
//  - global SRC operand = PER-LANE address (must include lane*16).
//  - one call moves exactly 1KB per wave. Zero VGPR cost — the only batching that
//    works in this kernel's tight-register regime.
static __device__ __forceinline__ void stage16(const void* g, void* l) {
    __builtin_amdgcn_global_load_lds(
        (const __attribute__((address_space(1))) void*)g,
        (__attribute__((address_space(3))) void*)l, 16, 0, 0);
}

// ---------------- Kernel 1a: eprep — coalesced read + LDS permute + g ---------------
// LINEAR coalesced f32x4 read, permute via LDS, LINEAR coalesced ushort4 write.
// ebf frag layout (R13-verified): within tile (n,T) [2048B]: byte kf*1024 + lane*16
// is lane(quad,r)'s A-frag half; chunk h*128+q*32+r*2+jh holds E[v=T*16+r][c4=h*8+q*2+jh].
// g[n][v] = E[n][v,:].dec_w via 16-lane shfl row groups.
__global__ void eprep(const float* __restrict__ emb, const float* __restrict__ dec_w,
                      unsigned short* __restrict__ ebf, float* __restrict__ g) {
    __shared__ ushort4 lu[256];
    __shared__ float red[16];
    int tid = threadIdx.x;
    int nt  = blockIdx.x;                 // n*1024 + T  (grid 8192)
    int n   = nt >> 10;
    int r   = tid >> 4;                   // row within 16-row tile
    int c4  = tid & 15;                   // f32x4 column
    f32x4 vv = ((const f32x4*)emb)[(size_t)nt * 256 + tid];   // LINEAR read
    ushort4 u = make_ushort4(f2bf(vv.x), f2bf(vv.y), f2bf(vv.z), f2bf(vv.w));
    int h = c4 >> 3, q = (c4 >> 1) & 3, jh = c4 & 1;
    lu[h * 128 + q * 32 + r * 2 + jh] = u;                    // permute via LDS
    const float* dw = dec_w + n * 64 + c4 * 4;
    float p = vv.x * dw[0] + vv.y * dw[1] + vv.z * dw[2] + vv.w * dw[3];
    p += __shfl_xor(p, 1); p += __shfl_xor(p, 2);
    p += __shfl_xor(p, 4); p += __shfl_xor(p, 8);             // 16-lane row group
    if (c4 == 0) red[r] = p;
    __syncthreads();
    ((ushort4*)ebf)[(size_t)nt * 256 + tid] = lu[tid];        // LINEAR write
    if (tid < 16) g[n * VOCAB + (nt & 1023) * 16 + tid] = red[tid];
}

// ---------------- Kernel 1b: qprep — one wave per t (grid 512 x 64) ------------------
// Frag-ordered 64-q granules (R15/R19-verified):
//   short idx = (n*32 + q>>6)*4096 + ((qt*2+kf)*4 + quad)*128 + l15*8 + j
__global__ void qprep(const float* __restrict__ x, const float* __restrict__ enc_w,
                      const float* __restrict__ enc_b, const float* __restrict__ ln_w,
                      const float* __restrict__ ln_b, unsigned short* __restrict__ qbf) {
    int h = threadIdx.x;                  // block = one wave (64)
    int t = blockIdx.x;                   // grid 512
    float h2  = (float)(h & ~1);
    float div = __expf(h2 * (-9.210340371976184f / 64.0f));
    float ang = (float)t * div;
    float pe  = (h & 1) ? __cosf(ang) : __sinf(ang);
    float lw = ln_w[h], lb = ln_b[h];
    int kf = h >> 5, quad = (h >> 3) & 3, j = h & 7;
    int fragoff = ((kf * 4 + quad) * 128) + j;   // + qt*1024 + l15*8 added per row
    #pragma unroll
    for (int n = 0; n < NH; ++n) {
        float ew = enc_w[n * 64 + h];
        float eb = enc_b[n * 64 + h];
        #pragma unroll
        for (int b = 0; b < 4; ++b) {
            int q = b * 512 + t;
            float v = x[q] * ew + eb + pe;
            float s = v;
            #pragma unroll
            for (int off = 1; off < 64; off <<= 1) s += __shfl_xor(s, off);
            float mu = s * (1.0f / 64.0f);
            float dd = v - mu;
            float s2 = dd * dd;
            #pragma unroll
            for (int off = 1; off < 64; off <<= 1) s2 += __shfl_xor(s2, off);
            float var = s2 * (1.0f / 64.0f);
            float y = dd * rsqrtf(var + 1e-5f) * lw + lb;
            int qt = (q >> 4) & 3, l15 = q & 15;
            size_t idx = ((size_t)(n * 32 + (q >> 6)) * 4096)
                       + qt * 1024 + l15 * 8 + fragoff;
            qbf[idx] = f2bf(y * QSCALE);
        }
    }
}

// ---------------- Kernel 2: attn (R20 — wave-private dbuf + counted vmcnt, 0 barriers)
// grid 512 = qchunk(8)*64 + vgroup(8)*8 + head(8); block 256 (4 waves).
// blockIdx % 8 == head: XCD-pinned (head's ebf 2MB + qbf 256KB L2-fit).
// WAVE owns 64 q (private 8KB Q in LDS) x 2048 v, swept as 64 tiles of 32 v (4KB).
// Per tile: issue 4 stage16 for tile t+1 into the other half of the wave-PRIVATE
// 8KB E double-buffer, then `s_waitcnt vmcnt(4)` — counted, never drained to 0:
// tile t's DMA had the whole previous tile body (~500cy) to land, so the wait is
// ~free. NO BARRIERS in the loop (Q/E wave-private; g shared read-only after one
// prologue barrier). This is T4 pipelining with ZERO register cost — the structure
// R14 (reg prefetch, spilled 190MB) and R18/R19 (shared buffer, barrier convoy +8us
// VALU) could not reach.
// LDS 72KB -> exactly 2 blocks/CU; grid 512 = one tranche. launch_bounds(256,2)
// permits up to 256 VGPRs — the (256,4) 64-reg ceiling no longer binds; a-frags
// (32 regs) held across the qt loop amortize E LDS reads 4x. If the allocator
// still demotes them, degradation is extra LDS reads — graceful, not scratch.
// Race-freedom (wave-local, no cross-wave sharing of E/Q):
//  - stage(t+1) writes buf[(t+1)&1]; reads of buf[t&1] are disjoint.
//  - buf[(t+1)&1] was last read at tile t-1, whose ds_reads completed before the
//    MFMAs consuming them (compiler lgkmcnt) — all before stage(t+1) issues.
//  - vmcnt(4) allows the 4 just-issued loads, requires all older done = tile t ready.
// t=63 prefetch reads 4KB past esrc end — lands in g region of ws (allocated,
// values unused, no fault).
// TRIPWIRE: WRITE_SIZE must be ~1024KB (part is 1MB now); >>1MB = spill returned.
__global__ void __launch_bounds__(256, 2)
attn(const unsigned short* __restrict__ qbf, const unsigned short* __restrict__ ebf,
     const float* __restrict__ g, float2* __restrict__ part) {
    __shared__ __attribute__((aligned(16))) char smem[73728];
    int tid  = threadIdx.x;
    int w    = tid >> 6;
    int lane = tid & 63;
    int quad = lane >> 4;
    int l15  = lane & 15;
    int head   = blockIdx.x & 7;
    int vgroup = (blockIdx.x >> 3) & 7;    // 8 groups x 2048 v
    int qchunk = blockIdx.x >> 6;          // 8 chunks x 256 q (64 per wave)

    char*  eb = smem + w * 8192;           // wave-private E double-buffer [2][4096]
    char*  qw = smem + 32768 + w * 8192;   // wave-private Q (8KB = 4 q-tiles)
    float* gl = (float*)(smem + 65536);    // shared g slice (8KB = 2048 floats)

    const char* qsrc = (const char*)qbf + (size_t)(head * 32 + qchunk * 4 + w) * 8192;
    const char* esrc = (const char*)ebf + (size_t)head * 2097152 + (size_t)vgroup * 262144;
    const char* gsrc = (const char*)(g + head * VOCAB + vgroup * 2048);

    // prologue: Q (8 calls), g (2 calls/wave, shared), E tile 0 (4 calls).
    // Dest wave-uniform (HW adds lane*16); src per-lane (+lane*16).
    #pragma unroll
    for (int c = 0; c < 8; ++c)
        stage16(qsrc + c * 1024 + lane * 16, qw + c * 1024);
    stage16(gsrc + (w * 2)     * 1024 + lane * 16, (char*)gl + (w * 2)     * 1024);
    stage16(gsrc + (w * 2 + 1) * 1024 + lane * 16, (char*)gl + (w * 2 + 1) * 1024);
    #pragma unroll
    for (int c = 0; c < 4; ++c)
        stage16(esrc + c * 1024 + lane * 16, eb + c * 1024);
    __syncthreads();   // drains all prologue DMA (vmcnt 0) + publishes shared g

    float num[4] = {0.f, 0.f, 0.f, 0.f};
    float den[4] = {0.f, 0.f, 0.f, 0.f};
    const f32x4 z = {0.f, 0.f, 0.f, 0.f};
    const char*  el   = eb + lane * 16;    // E read base (+parity*4096 +{0..3072})
    const char*  qr   = qw + lane * 16;    // Q read base (+qt*2048 +{0,1024})
    const float* glq  = gl + quad * 4;     // g read base (+t*32 +{0,16})
    const char*  srcp = esrc + 4096 + lane * 16;   // tile-1 src, += 4096/tile

    #pragma clang loop unroll(disable)
    for (int t = 0; t < 64; ++t) {
        // issue next tile's DMA into the other buffer half (4KB, zero regs)
        char* pd = eb + ((t + 1) & 1) * 4096;
        stage16(srcp,        pd);
        stage16(srcp + 1024, pd + 1024);
        stage16(srcp + 2048, pd + 2048);
        stage16(srcp + 3072, pd + 3072);
        srcp += 4096;
        // counted wait: 4 newest (t+1) may fly; all older (tile t) must have landed.
        // memory clobber also pins the Q/E ds_reads below this point per-iteration
        // (anti-LICM — the R11/R13 spill-avoidance discipline).
        asm volatile("s_waitcnt vmcnt(4)" ::: "memory");
        __builtin_amdgcn_sched_barrier(0);

        const char* ebb = el + (t & 1) * 4096;
        bf16x8 a00 = *(const bf16x8*)(ebb);           // v-tile 0, k 0..31
        bf16x8 a01 = *(const bf16x8*)(ebb + 1024);    // v-tile 0, k 32..63
        bf16x8 a10 = *(const bf16x8*)(ebb + 2048);    // v-tile 1, k 0..31
        bf16x8 a11 = *(const bf16x8*)(ebb + 3072);    // v-tile 1, k 32..63
        f32x4 gv0 = *(const f32x4*)(glq + t * 32);
        f32x4 gv1 = *(const f32x4*)(glq + t * 32 + 16);

        #pragma unroll
        for (int qt = 0; qt < 4; ++qt) {
            bf16x8 q0 = *(const bf16x8*)(qr + qt * 2048);
            bf16x8 q1 = *(const bf16x8*)(qr + qt * 2048 + 1024);
            f32x4 acc0 = __builtin_amdgcn_mfma_f32_16x16x32_bf16(a00, q0, z, 0, 0, 0);
            acc0       = __builtin_amdgcn_mfma_f32_16x16x32_bf16(a01, q1, acc0, 0, 0, 0);
            f32x4 acc1 = __builtin_amdgcn_mfma_f32_16x16x32_bf16(a10, q0, z, 0, 0, 0);
            acc1       = __builtin_amdgcn_mfma_f32_16x16x32_bf16(a11, q1, acc1, 0, 0, 0);
            // D layout: col=l15=q, row=quad*4+r = v-within-16-tile
            #pragma unroll
            for (int r = 0; r < 4; ++r) {
                float p0 = fexp2(acc0[r]);
                float p1 = fexp2(acc1[r]);
                den[qt] += p0 + p1;
                num[qt] += p0 * gv0[r] + p1 * gv1[r];
            }
        }
    }

    // reduce across quads (same l15 = same q)
    #pragma unroll
    for (int qt = 0; qt < 4; ++qt) {
        num[qt] += __shfl_xor(num[qt], 16); num[qt] += __shfl_xor(num[qt], 32);
        den[qt] += __shfl_xor(den[qt], 16); den[qt] += __shfl_xor(den[qt], 32);
    }
    // quad c commits q-tile c (static select chain — no runtime array index)
    float nv = quad == 0 ? num[0] : quad == 1 ? num[1] : quad == 2 ? num[2] : num[3];
    float dv = quad == 0 ? den[0] : quad == 1 ? den[1] : quad == 2 ? den[2] : den[3];
    int qg = qchunk * 256 + w * 64 + quad * 16 + l15;
    part[((size_t)vgroup * NH + head) * QPH + qg] = make_float2(nv, dv);
}

// ---------------- Kernel 3: fin — parallel over (n,q), LDS reduce over n -------------
__global__ void fin(const float2* __restrict__ part, const float* __restrict__ dec_b,
                    float* __restrict__ out) {
    __shared__ float red[8][32];
    int t  = threadIdx.x;
    int ql = t & 31;
    int n  = t >> 5;
    int q  = blockIdx.x * 32 + ql;
    float nv = 0.f, dv = 0.f;
    #pragma unroll            // full unroll: 8 outstanding 8B loads
    for (int sl = 0; sl < NVG; ++sl) {
        float2 nd = part[((size_t)sl * NH + n) * QPH + q];
        nv += nd.x; dv += nd.y;
    }
    red[n][ql] = nv / dv;
    __syncthreads();
    if (t < 32) {
        float s = dec_b[0];
        #pragma unroll
        for (int m = 0; m < NH; ++m) s += red[m][t];
        out[q] = s;
    }
}

extern "C" void kernel_launch(void* const* d_in, const int* in_sizes, int n_in,
                              void* d_out, int out_size, void* d_ws, size_t ws_size,
                              hipStream_t stream) {
    const float* x     = (const float*)d_in[0];
    const float* emb   = (const float*)d_in[1];
    const float* enc_w = (const float*)d_in[2];
    const float* enc_b = (const float*)d_in[3];
    const float* ln_w  = (const float*)d_in[4];
    const float* ln_b  = (const float*)d_in[5];
    const float* dec_w = (const float*)d_in[6];
    const float* dec_b = (const float*)d_in[7];
    float* out = (float*)d_out;

    char* ws = (char*)d_ws;
    unsigned short* qbf  = (unsigned short*)(ws);                        // 2 MB
    unsigned short* ebf  = (unsigned short*)(ws + 2097152);              // 16 MB
    float*          g    = (float*)(ws + 2097152 + 16777216);            // 512 KB
    float2*         part = (float2*)(ws + 2097152 + 16777216 + 524288);  // 1 MB (8*8*2048)

    hipLaunchKernelGGL(eprep, dim3(8192), dim3(256), 0, stream, emb, dec_w, ebf, g);
    hipLaunchKernelGGL(qprep, dim3(512),  dim3(64),  0, stream, x, enc_w, enc_b, ln_w, ln_b, qbf);
    hipLaunchKernelGGL(attn,  dim3(512),  dim3(256), 0, stream, qbf, ebf, g, part);
    hipLaunchKernelGGL(fin,   dim3(64),   dim3(256), 0, stream, part, dec_b, out);
}

// Round 11
// 159.019 us; speedup vs baseline: 1.0089x; 1.0089x over previous
//
#include <hip/hip_runtime.h>
#include <hip/hip_bf16.h>
#include <math.h>

#define NH 8
#define HS 64
#define VOCAB 16384
#define QPH 2048                         // queries per head = b(4) * t(512)
#define NVG 8                            // vocab groups (2048 rows each)
// fold 1/sqrt(512) * log2(e) into Q so the epilogue is p = exp2(score)
#define QSCALE (0.04419417382415922f * 1.4426950408889634f)

typedef __attribute__((ext_vector_type(8))) short bf16x8;
typedef __attribute__((ext_vector_type(4))) float f32x4;

static __device__ __forceinline__ unsigned short f2bf(float f) {
    __hip_bfloat16 h = __float2bfloat16(f);
    unsigned short u;
    __builtin_memcpy(&u, &h, 2);
    return u;
}

static __device__ __forceinline__ float fexp2(float x) {
#if __has_builtin(__builtin_amdgcn_exp2f)
    return __builtin_amdgcn_exp2f(x);     // v_exp_f32 directly
#else
    return __expf(x * 0.6931471805599453f);
#endif
}

// async global->LDS. HW semantics (hard-won over R12/R16/R17):
//  - LDS dest operand = WAVE-UNIFORM base; HW adds lane*16 (divergent dest -> fault).
//  - global SRC operand = PER-LANE address (must include lane*16).
//  - one call moves exactly 1KB per wave. Zero VGPR cost.
static __device__ __forceinline__ void stage16(const void* g, void* l) {
    __builtin_amdgcn_global_load_lds(
        (const __attribute__((address_space(1))) void*)g,
        (__attribute__((address_space(3))) void*)l, 16, 0, 0);
}

// ---------------- Kernel 1: prep — eprep (blocks 0..8191) + qprep (8192..8319) -------
// Merged: saves a launch gap; eprep (memory-bound) and qprep (trans-bound) co-schedule.
// eprep: LINEAR f32x4 read -> LDS permute -> LINEAR ushort4 write (R13-verified frag
// layout: tile (n,T) 2048B, byte kf*1024+lane*16 = lane(quad,r)'s A-frag half).
// g[n][v] = E[n][v,:].dec_w via 16-lane shfl groups.
// qprep: one wave per t; pe computed once; frag-ordered 64-q granules (R15-verified):
//   short idx = (n*32 + q>>6)*4096 + ((qt*2+kf)*4 + quad)*128 + l15*8 + j
__global__ void prep(const float* __restrict__ emb, const float* __restrict__ dec_w,
                     const float* __restrict__ x, const float* __restrict__ enc_w,
                     const float* __restrict__ enc_b, const float* __restrict__ ln_w,
                     const float* __restrict__ ln_b,
                     unsigned short* __restrict__ ebf, float* __restrict__ g,
                     unsigned short* __restrict__ qbf) {
    __shared__ ushort4 lu[256];
    __shared__ float red[16];
    int tid = threadIdx.x;
    if (blockIdx.x < 8192) {              // ---- eprep body ----
        int nt  = blockIdx.x;             // n*1024 + T
        int n   = nt >> 10;
        int r   = tid >> 4;
        int c4  = tid & 15;
        f32x4 vv = ((const f32x4*)emb)[(size_t)nt * 256 + tid];   // LINEAR read
        ushort4 u = make_ushort4(f2bf(vv.x), f2bf(vv.y), f2bf(vv.z), f2bf(vv.w));
        int h = c4 >> 3, q = (c4 >> 1) & 3, jh = c4 & 1;
        lu[h * 128 + q * 32 + r * 2 + jh] = u;                    // permute via LDS
        const float* dw = dec_w + n * 64 + c4 * 4;
        float p = vv.x * dw[0] + vv.y * dw[1] + vv.z * dw[2] + vv.w * dw[3];
        p += __shfl_xor(p, 1); p += __shfl_xor(p, 2);
        p += __shfl_xor(p, 4); p += __shfl_xor(p, 8);
        if (c4 == 0) red[r] = p;
        __syncthreads();
        ((ushort4*)ebf)[(size_t)nt * 256 + tid] = lu[tid];        // LINEAR write
        if (tid < 16) g[n * VOCAB + (nt & 1023) * 16 + tid] = red[tid];
    } else {                              // ---- qprep body (128 blocks x 4 waves) ----
        int h = tid & 63;
        int t = (blockIdx.x - 8192) * 4 + (tid >> 6);
        float h2  = (float)(h & ~1);
        float div = __expf(h2 * (-9.210340371976184f / 64.0f));
        float ang = (float)t * div;
        float pe  = (h & 1) ? __cosf(ang) : __sinf(ang);
        float lw = ln_w[h], lb = ln_b[h];
        int kf = h >> 5, quad = (h >> 3) & 3, j = h & 7;
        int fragoff = ((kf * 4 + quad) * 128) + j;
        #pragma unroll
        for (int n = 0; n < NH; ++n) {
            float ew = enc_w[n * 64 + h];
            float eb = enc_b[n * 64 + h];
            #pragma unroll
            for (int b = 0; b < 4; ++b) {
                int q = b * 512 + t;
                float v = x[q] * ew + eb + pe;
                float s = v;
                #pragma unroll
                for (int off = 1; off < 64; off <<= 1) s += __shfl_xor(s, off);
                float mu = s * (1.0f / 64.0f);
                float dd = v - mu;
                float s2 = dd * dd;
                #pragma unroll
                for (int off = 1; off < 64; off <<= 1) s2 += __shfl_xor(s2, off);
                float var = s2 * (1.0f / 64.0f);
                float y = dd * rsqrtf(var + 1e-5f) * lw + lb;
                int qt = (q >> 4) & 3, l15 = q & 15;
                size_t idx = ((size_t)(n * 32 + (q >> 6)) * 4096)
                           + qt * 1024 + l15 * 8 + fragoff;
                qbf[idx] = f2bf(y * QSCALE);
            }
        }
    }
}

// ---------------- Kernel 2: attn (R21 — R20 skeleton + Q in VGPRs) ------------------
// grid 512 = qchunk(8)*64 + vgroup(8)*8 + head(8); block 256 (4 waves).
// blockIdx % 8 == head: XCD-pinned. Wave owns 64q x 2048v, swept as 64 tiles of 32v
// via wave-private 8KB E dbuf + counted `s_waitcnt vmcnt(4)` (R20, verified correct,
// no spill). ZERO barriers in the loop.
// R21 vs R20 (65.8us): R20's pole was the LDS-READ PIPE, not VALU — 14 ds_read_b128
// per wave-tile x 12cy (m134) = ~37us/CU, because the anti-LICM clobber forced Q
// re-reads from LDS every tile (8/tile). At (256,2) the register budget is 256
// (VGPR=88, no spill) — the 64-reg curse was a (256,4) artifact. So:
//  - Q held in 32 VGPRs, loaded ONCE from global before the loop (frag-ordered qbf
//    makes each fragment a coalesced 1KB load at base + (qt*2+kf)*1024 + lane*16).
//    Q-LDS dropped entirely; LDS reads/tile 14 -> 6; LDS pipe ~37 -> ~16us/CU.
//  - values-in-regs flow through the vmcnt clobber (it orders MEMORY ops only).
// LDS 40KB (E 32 + g 8). TRIPWIRE: WRITE_SIZE must stay 1024KB exactly — bigger
// means the Q hoist spilled (then revert to LDS-Q). VGPR expected ~110-130.
__global__ void __launch_bounds__(256, 2)
attn(const unsigned short* __restrict__ qbf, const unsigned short* __restrict__ ebf,
     const float* __restrict__ g, float2* __restrict__ part) {
    __shared__ __attribute__((aligned(16))) char smem[32768 + 8192];
    int tid  = threadIdx.x;
    int w    = tid >> 6;
    int lane = tid & 63;
    int quad = lane >> 4;
    int l15  = lane & 15;
    int head   = blockIdx.x & 7;
    int vgroup = (blockIdx.x >> 3) & 7;    // 8 groups x 2048 v
    int qchunk = blockIdx.x >> 6;          // 8 chunks x 256 q (64 per wave)

    char*  eb = smem + w * 8192;           // wave-private E double-buffer [2][4096]
    float* gl = (float*)(smem + 32768);    // shared g slice (8KB = 2048 floats)

    const char* qsrc = (const char*)qbf + (size_t)(head * 32 + qchunk * 4 + w) * 8192;
    const char* esrc = (const char*)ebf + (size_t)head * 2097152 + (size_t)vgroup * 262144;
    const char* gsrc = (const char*)(g + head * VOCAB + vgroup * 2048);

    // prologue DMA: g (2 calls/wave, shared 8KB) + E tile 0 (4 calls, private 4KB).
    stage16(gsrc + (w * 2)     * 1024 + lane * 16, (char*)gl + (w * 2)     * 1024);
    stage16(gsrc + (w * 2 + 1) * 1024 + lane * 16, (char*)gl + (w * 2 + 1) * 1024);
    #pragma unroll
    for (int c = 0; c < 4; ++c)
        stage16(esrc + c * 1024 + lane * 16, eb + c * 1024);
    __syncthreads();   // drains prologue DMA + publishes shared g

    // Q -> 32 VGPRs, once (global, coalesced, L2-resident; held across the loop)
    bf16x8 qf0[4], qf1[4];
    #pragma unroll
    for (int qt = 0; qt < 4; ++qt) {
        qf0[qt] = *(const bf16x8*)(qsrc + (qt * 2)     * 1024 + lane * 16);
        qf1[qt] = *(const bf16x8*)(qsrc + (qt * 2 + 1) * 1024 + lane * 16);
    }

    float num[4] = {0.f, 0.f, 0.f, 0.f};
    float den[4] = {0.f, 0.f, 0.f, 0.f};
    const f32x4 z = {0.f, 0.f, 0.f, 0.f};
    const char*  el   = eb + lane * 16;    // E read base (+parity*4096 +{0..3072})
    const float* glq  = gl + quad * 4;     // g read base (+t*32 +{0,16})
    const char*  srcp = esrc + 4096 + lane * 16;   // tile-1 src, += 4096/tile

    #pragma clang loop unroll(disable)
    for (int t = 0; t < 64; ++t) {
        // issue next tile's DMA into the other buffer half (4KB, zero regs)
        char* pd = eb + ((t + 1) & 1) * 4096;
        stage16(srcp,        pd);
        stage16(srcp + 1024, pd + 1024);
        stage16(srcp + 2048, pd + 2048);
        stage16(srcp + 3072, pd + 3072);
        srcp += 4096;
        // counted wait: 4 newest (tile t+1) may fly; all older (tile t) landed.
        // memory clobber pins the E/gv ds_reads below per-iteration; Q values are
        // in registers and flow through freely.
        asm volatile("s_waitcnt vmcnt(4)" ::: "memory");
        __builtin_amdgcn_sched_barrier(0);

        const char* ebb = el + (t & 1) * 4096;
        bf16x8 a00 = *(const bf16x8*)(ebb);           // v-tile 0, k 0..31
        bf16x8 a01 = *(const bf16x8*)(ebb + 1024);    // v-tile 0, k 32..63
        bf16x8 a10 = *(const bf16x8*)(ebb + 2048);    // v-tile 1, k 0..31
        bf16x8 a11 = *(const bf16x8*)(ebb + 3072);    // v-tile 1, k 32..63
        f32x4 gv0 = *(const f32x4*)(glq + t * 32);
        f32x4 gv1 = *(const f32x4*)(glq + t * 32 + 16);

        #pragma unroll
        for (int qt = 0; qt < 4; ++qt) {
            f32x4 acc0 = __builtin_amdgcn_mfma_f32_16x16x32_bf16(a00, qf0[qt], z, 0, 0, 0);
            acc0       = __builtin_amdgcn_mfma_f32_16x16x32_bf16(a01, qf1[qt], acc0, 0, 0, 0);
            f32x4 acc1 = __builtin_amdgcn_mfma_f32_16x16x32_bf16(a10, qf0[qt], z, 0, 0, 0);
            acc1       = __builtin_amdgcn_mfma_f32_16x16x32_bf16(a11, qf1[qt], acc1, 0, 0, 0);
            // D layout: col=l15=q, row=quad*4+r = v-within-16-tile
            #pragma unroll
            for (int r = 0; r < 4; ++r) {
                float p0 = fexp2(acc0[r]);
                float p1 = fexp2(acc1[r]);
                den[qt] += p0 + p1;
                num[qt] += p0 * gv0[r] + p1 * gv1[r];
            }
        }
    }

    // reduce across quads (same l15 = same q)
    #pragma unroll
    for (int qt = 0; qt < 4; ++qt) {
        num[qt] += __shfl_xor(num[qt], 16); num[qt] += __shfl_xor(num[qt], 32);
        den[qt] += __shfl_xor(den[qt], 16); den[qt] += __shfl_xor(den[qt], 32);
    }
    // quad c commits q-tile c (static select chain — no runtime array index)
    float nv = quad == 0 ? num[0] : quad == 1 ? num[1] : quad == 2 ? num[2] : num[3];
    float dv = quad == 0 ? den[0] : quad == 1 ? den[1] : quad == 2 ? den[2] : den[3];
    int qg = qchunk * 256 + w * 64 + quad * 16 + l15;
    part[((size_t)vgroup * NH + head) * QPH + qg] = make_float2(nv, dv);
}

// ---------------- Kernel 3: fin — parallel over (n,q), LDS reduce over n -------------
__global__ void fin(const float2* __restrict__ part, const float* __restrict__ dec_b,
                    float* __restrict__ out) {
    __shared__ float red[8][32];
    int t  = threadIdx.x;
    int ql = t & 31;
    int n  = t >> 5;
    int q  = blockIdx.x * 32 + ql;
    float nv = 0.f, dv = 0.f;
    #pragma unroll            // full unroll: 8 outstanding 8B loads
    for (int sl = 0; sl < NVG; ++sl) {
        float2 nd = part[((size_t)sl * NH + n) * QPH + q];
        nv += nd.x; dv += nd.y;
    }
    red[n][ql] = nv / dv;
    __syncthreads();
    if (t < 32) {
        float s = dec_b[0];
        #pragma unroll
        for (int m = 0; m < NH; ++m) s += red[m][t];
        out[q] = s;
    }
}

extern "C" void kernel_launch(void* const* d_in, const int* in_sizes, int n_in,
                              void* d_out, int out_size, void* d_ws, size_t ws_size,
                              hipStream_t stream) {
    const float* x     = (const float*)d_in[0];
    const float* emb   = (const float*)d_in[1];
    const float* enc_w = (const float*)d_in[2];
    const float* enc_b = (const float*)d_in[3];
    const float* ln_w  = (const float*)d_in[4];
    const float* ln_b  = (const float*)d_in[5];
    const float* dec_w = (const float*)d_in[6];
    const float* dec_b = (const float*)d_in[7];
    float* out = (float*)d_out;

    char* ws = (char*)d_ws;
    unsigned short* qbf  = (unsigned short*)(ws);                        // 2 MB
    unsigned short* ebf  = (unsigned short*)(ws + 2097152);              // 16 MB
    float*          g    = (float*)(ws + 2097152 + 16777216);            // 512 KB
    float2*         part = (float2*)(ws + 2097152 + 16777216 + 524288);  // 1 MB (8*8*2048)

    hipLaunchKernelGGL(prep, dim3(8320), dim3(256), 0, stream,
                       emb, dec_w, x, enc_w, enc_b, ln_w, ln_b, ebf, g, qbf);
    hipLaunchKernelGGL(attn, dim3(512),  dim3(256), 0, stream, qbf, ebf, g, part);
    hipLaunchKernelGGL(fin,  dim3(64),   dim3(256), 0, stream, part, dec_b, out);
}